// Round 1
// baseline (2635.846 us; speedup 1.0000x reference)
//
#include <hip/hip_runtime.h>

#define NB 1024   // batch
#define TT 32     // encoder length
#define DIN 256   // input dim
#define HD 256    // hidden dim
#define NC 38     // classes
#define NSTEP 26  // decode steps

#define TM 64
#define TN 64
#define TK 16

__device__ __forceinline__ float sigmoidf_(float x) {
    return 1.0f / (1.0f + expf(-x));
}

// ---------------------------------------------------------------------------
// K1: H_proj[m][n] = sum_k enc[m][k] * w_i2h[n][k];  M=32768, N=256, K=256
// ---------------------------------------------------------------------------
__global__ __launch_bounds__(256) void hproj_kernel(
    const float* __restrict__ A, const float* __restrict__ Bw,
    float* __restrict__ Cout)
{
    __shared__ float As[TK][TM + 4];
    __shared__ float Bs[TK][TN + 4];
    const int m0 = blockIdx.x * TM;
    const int n0 = blockIdx.y * TN;
    const int tid = threadIdx.x;
    const int tx = tid & 15, ty = tid >> 4;

    float acc[4][4] = {};

    for (int kc = 0; kc < DIN; kc += TK) {
#pragma unroll
        for (int i = 0; i < 4; i++) {
            int idx = tid + i * 256;
            int k = idx & 15, r = idx >> 4;
            As[k][r] = A[(size_t)(m0 + r) * DIN + kc + k];
            Bs[k][r] = Bw[(size_t)(n0 + r) * DIN + kc + k];
        }
        __syncthreads();
#pragma unroll
        for (int k = 0; k < TK; k++) {
            float4 a4 = *(const float4*)&As[k][ty * 4];
            float4 b4 = *(const float4*)&Bs[k][tx * 4];
            float av[4] = {a4.x, a4.y, a4.z, a4.w};
            float bv[4] = {b4.x, b4.y, b4.z, b4.w};
#pragma unroll
            for (int i = 0; i < 4; i++)
#pragma unroll
                for (int j = 0; j < 4; j++)
                    acc[i][j] += av[i] * bv[j];
        }
        __syncthreads();
    }
#pragma unroll
    for (int i = 0; i < 4; i++) {
        int row = m0 + ty * 4 + i;
        float4 v = make_float4(acc[i][0], acc[i][1], acc[i][2], acc[i][3]);
        *(float4*)&Cout[(size_t)row * 256 + n0 + tx * 4] = v;
    }
}

// ---------------------------------------------------------------------------
// K3: gates[b][j] = sum_k x[b][k]*Wcat[j][k] + b_ih[j]+b_hh[j] + onehot col
//     x = [ctx | h] (K=512), Wcat = [w_ih[:, :256] | w_hh]
//     M=1024, N=1024. grid (16,16), block 256.
// ---------------------------------------------------------------------------
__global__ __launch_bounds__(256) void gates_kernel(
    const float* __restrict__ ctx, const float* __restrict__ h,
    const float* __restrict__ w_ih, const float* __restrict__ w_hh,
    const float* __restrict__ b_ih, const float* __restrict__ b_hh,
    const int* __restrict__ text, int step, float* __restrict__ gates)
{
    __shared__ float As[TK][TM + 4];
    __shared__ float Bs[TK][TN + 4];
    const int m0 = blockIdx.x * TM;
    const int n0 = blockIdx.y * TN;
    const int tid = threadIdx.x;
    const int tx = tid & 15, ty = tid >> 4;

    float acc[4][4] = {};

    for (int kc = 0; kc < 512; kc += TK) {
#pragma unroll
        for (int i = 0; i < 4; i++) {
            int idx = tid + i * 256;
            int k = idx & 15, r = idx >> 4;
            int kk = kc + k;
            float av, bv;
            if (kk < 256) {
                av = ctx[(size_t)(m0 + r) * 256 + kk];
                bv = w_ih[(size_t)(n0 + r) * 294 + kk];
            } else {
                av = h[(size_t)(m0 + r) * 256 + (kk - 256)];
                bv = w_hh[(size_t)(n0 + r) * 256 + (kk - 256)];
            }
            As[k][r] = av;
            Bs[k][r] = bv;
        }
        __syncthreads();
#pragma unroll
        for (int k = 0; k < TK; k++) {
            float4 a4 = *(const float4*)&As[k][ty * 4];
            float4 b4 = *(const float4*)&Bs[k][tx * 4];
            float av[4] = {a4.x, a4.y, a4.z, a4.w};
            float bv[4] = {b4.x, b4.y, b4.z, b4.w};
#pragma unroll
            for (int i = 0; i < 4; i++)
#pragma unroll
                for (int j = 0; j < 4; j++)
                    acc[i][j] += av[i] * bv[j];
        }
        __syncthreads();
    }

#pragma unroll
    for (int i = 0; i < 4; i++) {
        int b = m0 + ty * 4 + i;
        int cls = text[b * NSTEP + step];
        int j0 = n0 + tx * 4;
        float4 v;
        v.x = acc[i][0] + b_ih[j0 + 0] + b_hh[j0 + 0] + w_ih[(size_t)(j0 + 0) * 294 + 256 + cls];
        v.y = acc[i][1] + b_ih[j0 + 1] + b_hh[j0 + 1] + w_ih[(size_t)(j0 + 1) * 294 + 256 + cls];
        v.z = acc[i][2] + b_ih[j0 + 2] + b_hh[j0 + 2] + w_ih[(size_t)(j0 + 2) * 294 + 256 + cls];
        v.w = acc[i][3] + b_ih[j0 + 3] + b_hh[j0 + 3] + w_ih[(size_t)(j0 + 3) * 294 + 256 + cls];
        *(float4*)&gates[(size_t)b * 1024 + j0] = v;
    }
}

// ---------------------------------------------------------------------------
// K2': fused {LSTM(step-1) + probs(step-1)} + attention(step) -> ctx
//      grid 128 blocks x 256 threads, 8 batch rows per block.
//      step == NSTEP: only LSTM+probs for the last step.
// ---------------------------------------------------------------------------
#define BPB 8
__global__ __launch_bounds__(256) void attn_kernel(
    const float* __restrict__ enc, const float* __restrict__ Hproj,
    const float* __restrict__ w_h2h, const float* __restrict__ b_h2h,
    const float* __restrict__ w_score,
    const float* __restrict__ w_gen, const float* __restrict__ b_gen,
    const float* __restrict__ gates,
    float* __restrict__ h, float* __restrict__ c,
    float* __restrict__ ctx, float* __restrict__ probs, int step)
{
    __shared__ float hsh[BPB][HD];
    __shared__ float hpsh[BPB][HD];
    __shared__ float esh[BPB][TT];
    __shared__ float wssh[HD];

    const int tid = threadIdx.x;
    const int b0 = blockIdx.x * BPB;

    wssh[tid] = w_score[tid];  // blockDim == HD == 256

    if (step > 0) {
        // LSTM update for step-1
#pragma unroll
        for (int it = 0; it < BPB; it++) {
            int idx = tid + it * 256;
            int bl = idx >> 8, hh = idx & 255;
            int b = b0 + bl;
            float gi = gates[(size_t)b * 1024 + hh];
            float gf = gates[(size_t)b * 1024 + 256 + hh];
            float gg = gates[(size_t)b * 1024 + 512 + hh];
            float go = gates[(size_t)b * 1024 + 768 + hh];
            float cv = c[(size_t)b * HD + hh];
            float cn = sigmoidf_(gf) * cv + sigmoidf_(gi) * tanhf(gg);
            float hn = sigmoidf_(go) * tanhf(cn);
            c[(size_t)b * HD + hh] = cn;
            h[(size_t)b * HD + hh] = hn;
            hsh[bl][hh] = hn;
        }
        __syncthreads();
        // probs for step-1: 32 threads per batch row
        {
            int bl = tid >> 5, j = tid & 31;
            for (int jj = j; jj < NC; jj += 32) {
                float s = b_gen[jj];
                const float* wg = &w_gen[(size_t)jj * HD];
                for (int d = 0; d < HD; d += 4) {
                    float4 wv = *(const float4*)&wg[d];
                    float4 hv = *(const float4*)&hsh[bl][d];
                    s += wv.x * hv.x + wv.y * hv.y + wv.z * hv.z + wv.w * hv.w;
                }
                probs[((size_t)(b0 + bl) * NSTEP + (step - 1)) * NC + jj] = s;
            }
        }
    } else {
        // h is zero-initialized in ws
#pragma unroll
        for (int it = 0; it < BPB; it++) {
            int idx = tid + it * 256;
            int bl = idx >> 8, hh = idx & 255;
            hsh[bl][hh] = h[(size_t)(b0 + bl) * HD + hh];
        }
    }
    __syncthreads();
    if (step >= NSTEP) return;

    // phase 1: hp[b][j] for j = tid
    {
        float acc[BPB];
#pragma unroll
        for (int bl = 0; bl < BPB; bl++) acc[bl] = 0.0f;
        const float* wr = &w_h2h[(size_t)tid * HD];
        for (int d = 0; d < HD; d += 4) {
            float4 wv = *(const float4*)&wr[d];
#pragma unroll
            for (int bl = 0; bl < BPB; bl++) {
                float4 hv = *(const float4*)&hsh[bl][d];
                acc[bl] += wv.x * hv.x + wv.y * hv.y + wv.z * hv.z + wv.w * hv.w;
            }
        }
        float bb = b_h2h[tid];
#pragma unroll
        for (int bl = 0; bl < BPB; bl++) hpsh[bl][tid] = acc[bl] + bb;
    }
    __syncthreads();

    // phase 2: e[b][t], one (b,t) per thread
    {
        int bl = tid >> 5, t = tid & 31;
        const float* hp = &Hproj[((size_t)(b0 + bl) * TT + t) * HD];
        float e = 0.0f;
        for (int d = 0; d < HD; d += 4) {
            float4 hv = *(const float4*)&hp[d];
            float4 pv = *(const float4*)&hpsh[bl][d];
            float4 wv = *(const float4*)&wssh[d];
            e += wv.x * tanhf(hv.x + pv.x);
            e += wv.y * tanhf(hv.y + pv.y);
            e += wv.z * tanhf(hv.z + pv.z);
            e += wv.w * tanhf(hv.w + pv.w);
        }
        esh[bl][t] = e;
    }
    __syncthreads();

    // phase 3: softmax over T for each b (one thread per b)
    if (tid < BPB) {
        float m = -1e30f;
        for (int t = 0; t < TT; t++) m = fmaxf(m, esh[tid][t]);
        float s = 0.0f;
        for (int t = 0; t < TT; t++) s += expf(esh[tid][t] - m);
        float inv = 1.0f / s;
        for (int t = 0; t < TT; t++) esh[tid][t] = expf(esh[tid][t] - m) * inv;
    }
    __syncthreads();

    // phase 4: context[b][d] = sum_t alpha[b][t]*enc[b][t][d]
    {
        int bl = tid >> 5, dg = tid & 31;
        int d0 = dg * 8;
        float4 a0 = make_float4(0.f, 0.f, 0.f, 0.f);
        float4 a1 = make_float4(0.f, 0.f, 0.f, 0.f);
        const float* er = &enc[(size_t)(b0 + bl) * TT * DIN];
        for (int t = 0; t < TT; t++) {
            float a = esh[bl][t];
            float4 e0 = *(const float4*)&er[t * DIN + d0];
            float4 e1 = *(const float4*)&er[t * DIN + d0 + 4];
            a0.x += a * e0.x; a0.y += a * e0.y; a0.z += a * e0.z; a0.w += a * e0.w;
            a1.x += a * e1.x; a1.y += a * e1.y; a1.z += a * e1.z; a1.w += a * e1.w;
        }
        *(float4*)&ctx[(size_t)(b0 + bl) * DIN + d0] = a0;
        *(float4*)&ctx[(size_t)(b0 + bl) * DIN + d0 + 4] = a1;
    }
}

// ---------------------------------------------------------------------------
extern "C" void kernel_launch(void* const* d_in, const int* in_sizes, int n_in,
                              void* d_out, int out_size, void* d_ws, size_t ws_size,
                              hipStream_t stream)
{
    const float* enc     = (const float*)d_in[0];
    const int*   text    = (const int*)d_in[1];
    // d_in[2] semantics: unused; d_in[3] is_train: unused (train mode)
    const float* w_i2h   = (const float*)d_in[4];
    const float* w_h2h   = (const float*)d_in[5];
    const float* b_h2h   = (const float*)d_in[6];
    const float* w_score = (const float*)d_in[7];
    const float* w_ih    = (const float*)d_in[8];
    const float* w_hh    = (const float*)d_in[9];
    const float* b_ih    = (const float*)d_in[10];
    const float* b_hh    = (const float*)d_in[11];
    const float* w_gen   = (const float*)d_in[12];
    const float* b_gen   = (const float*)d_in[13];
    float* out = (float*)d_out;

    char* ws = (char*)d_ws;
    float* Hproj  = (float*)ws;                                   // 32 MB
    float* hbuf   = (float*)(ws + (size_t)NB * TT * HD * 4);      // 1 MB
    float* cbuf   = hbuf + (size_t)NB * HD;                       // 1 MB
    float* ctxbuf = cbuf + (size_t)NB * HD;                       // 1 MB
    float* gates  = ctxbuf + (size_t)NB * DIN;                    // 4 MB

    // zero h and c (contiguous)
    hipMemsetAsync(hbuf, 0, (size_t)2 * NB * HD * sizeof(float), stream);

    hproj_kernel<<<dim3(NB * TT / TM, DIN / TN), 256, 0, stream>>>(enc, w_i2h, Hproj);

    for (int s = 0; s < NSTEP; s++) {
        attn_kernel<<<NB / BPB, 256, 0, stream>>>(enc, Hproj, w_h2h, b_h2h, w_score,
                                                  w_gen, b_gen, gates, hbuf, cbuf,
                                                  ctxbuf, out, s);
        gates_kernel<<<dim3(NB / TM, 1024 / TN), 256, 0, stream>>>(ctxbuf, hbuf, w_ih, w_hh,
                                                                   b_ih, b_hh, text, s, gates);
    }
    // final LSTM + probs for step 25
    attn_kernel<<<NB / BPB, 256, 0, stream>>>(enc, Hproj, w_h2h, b_h2h, w_score,
                                              w_gen, b_gen, gates, hbuf, cbuf,
                                              ctxbuf, out, NSTEP);
}

// Round 2
// 2111.839 us; speedup vs baseline: 1.2481x; 1.2481x over previous
//
#include <hip/hip_runtime.h>

#define NB 1024   // batch
#define TT 32     // encoder length
#define DIN 256   // input dim
#define HD 256    // hidden dim
#define NC 38     // classes
#define NSTEP 26  // decode steps

#define TM 64
#define TN 64
#define TK 16

__device__ __forceinline__ float sigmoidf_(float x) {
    return 1.0f / (1.0f + expf(-x));
}

// ---------------------------------------------------------------------------
// K1: H_proj[m][n] = sum_k enc[m][k] * w_i2h[n][k];  M=32768, N=256, K=256
// ---------------------------------------------------------------------------
__global__ __launch_bounds__(256) void hproj_kernel(
    const float* __restrict__ A, const float* __restrict__ Bw,
    float* __restrict__ Cout)
{
    __shared__ float As[TK][TM + 4];
    __shared__ float Bs[TK][TN + 4];
    const int m0 = blockIdx.x * TM;
    const int n0 = blockIdx.y * TN;
    const int tid = threadIdx.x;
    const int tx = tid & 15, ty = tid >> 4;

    float acc[4][4] = {};

    for (int kc = 0; kc < DIN; kc += TK) {
#pragma unroll
        for (int i = 0; i < 4; i++) {
            int idx = tid + i * 256;
            int k = idx & 15, r = idx >> 4;
            As[k][r] = A[(size_t)(m0 + r) * DIN + kc + k];
            Bs[k][r] = Bw[(size_t)(n0 + r) * DIN + kc + k];
        }
        __syncthreads();
#pragma unroll
        for (int k = 0; k < TK; k++) {
            float4 a4 = *(const float4*)&As[k][ty * 4];
            float4 b4 = *(const float4*)&Bs[k][tx * 4];
            float av[4] = {a4.x, a4.y, a4.z, a4.w};
            float bv[4] = {b4.x, b4.y, b4.z, b4.w};
#pragma unroll
            for (int i = 0; i < 4; i++)
#pragma unroll
                for (int j = 0; j < 4; j++)
                    acc[i][j] += av[i] * bv[j];
        }
        __syncthreads();
    }
#pragma unroll
    for (int i = 0; i < 4; i++) {
        int row = m0 + ty * 4 + i;
        float4 v = make_float4(acc[i][0], acc[i][1], acc[i][2], acc[i][3]);
        *(float4*)&Cout[(size_t)row * 256 + n0 + tx * 4] = v;
    }
}

// ---------------------------------------------------------------------------
// K3: gates[b][j] = sum_k x[b][k]*Wcat[j][k] + b_ih[j]+b_hh[j] + onehot col
// ---------------------------------------------------------------------------
__global__ __launch_bounds__(256) void gates_kernel(
    const float* __restrict__ ctx, const float* __restrict__ h,
    const float* __restrict__ w_ih, const float* __restrict__ w_hh,
    const float* __restrict__ b_ih, const float* __restrict__ b_hh,
    const int* __restrict__ text, int step, float* __restrict__ gates)
{
    __shared__ float As[TK][TM + 4];
    __shared__ float Bs[TK][TN + 4];
    const int m0 = blockIdx.x * TM;
    const int n0 = blockIdx.y * TN;
    const int tid = threadIdx.x;
    const int tx = tid & 15, ty = tid >> 4;

    float acc[4][4] = {};

    for (int kc = 0; kc < 512; kc += TK) {
#pragma unroll
        for (int i = 0; i < 4; i++) {
            int idx = tid + i * 256;
            int k = idx & 15, r = idx >> 4;
            int kk = kc + k;
            float av, bv;
            if (kk < 256) {
                av = ctx[(size_t)(m0 + r) * 256 + kk];
                bv = w_ih[(size_t)(n0 + r) * 294 + kk];
            } else {
                av = h[(size_t)(m0 + r) * 256 + (kk - 256)];
                bv = w_hh[(size_t)(n0 + r) * 256 + (kk - 256)];
            }
            As[k][r] = av;
            Bs[k][r] = bv;
        }
        __syncthreads();
#pragma unroll
        for (int k = 0; k < TK; k++) {
            float4 a4 = *(const float4*)&As[k][ty * 4];
            float4 b4 = *(const float4*)&Bs[k][tx * 4];
            float av[4] = {a4.x, a4.y, a4.z, a4.w};
            float bv[4] = {b4.x, b4.y, b4.z, b4.w};
#pragma unroll
            for (int i = 0; i < 4; i++)
#pragma unroll
                for (int j = 0; j < 4; j++)
                    acc[i][j] += av[i] * bv[j];
        }
        __syncthreads();
    }

#pragma unroll
    for (int i = 0; i < 4; i++) {
        int b = m0 + ty * 4 + i;
        int cls = text[b * NSTEP + step];
        int j0 = n0 + tx * 4;
        float4 v;
        v.x = acc[i][0] + b_ih[j0 + 0] + b_hh[j0 + 0] + w_ih[(size_t)(j0 + 0) * 294 + 256 + cls];
        v.y = acc[i][1] + b_ih[j0 + 1] + b_hh[j0 + 1] + w_ih[(size_t)(j0 + 1) * 294 + 256 + cls];
        v.z = acc[i][2] + b_ih[j0 + 2] + b_hh[j0 + 2] + w_ih[(size_t)(j0 + 2) * 294 + 256 + cls];
        v.w = acc[i][3] + b_ih[j0 + 3] + b_hh[j0 + 3] + w_ih[(size_t)(j0 + 3) * 294 + 256 + cls];
        *(float4*)&gates[(size_t)b * 1024 + j0] = v;
    }
}

// ---------------------------------------------------------------------------
// K2a: recur = LSTM(step-1) + probs(step-1) + hp(step) = h @ w_h2h.T + b_h2h
//      128 blocks x 256 threads, 8 batch rows per block (w_h2h reuse x8).
// ---------------------------------------------------------------------------
#define BPB 8
__global__ __launch_bounds__(256) void recur_kernel(
    const float* __restrict__ gates,
    const float* __restrict__ w_h2h, const float* __restrict__ b_h2h,
    const float* __restrict__ w_gen, const float* __restrict__ b_gen,
    float* __restrict__ h, float* __restrict__ c,
    float* __restrict__ hp, float* __restrict__ probs, int step)
{
    __shared__ float hsh[BPB][HD];
    const int tid = threadIdx.x;
    const int b0 = blockIdx.x * BPB;

    if (step > 0) {
#pragma unroll
        for (int it = 0; it < BPB; it++) {
            int idx = tid + it * 256;
            int bl = idx >> 8, hh = idx & 255;
            int b = b0 + bl;
            float gi = gates[(size_t)b * 1024 + hh];
            float gf = gates[(size_t)b * 1024 + 256 + hh];
            float gg = gates[(size_t)b * 1024 + 512 + hh];
            float go = gates[(size_t)b * 1024 + 768 + hh];
            float cv = c[(size_t)b * HD + hh];
            float cn = sigmoidf_(gf) * cv + sigmoidf_(gi) * tanhf(gg);
            float hn = sigmoidf_(go) * tanhf(cn);
            c[(size_t)b * HD + hh] = cn;
            h[(size_t)b * HD + hh] = hn;
            hsh[bl][hh] = hn;
        }
        __syncthreads();
        // probs for step-1: 32 threads per batch row
        {
            int bl = tid >> 5, j = tid & 31;
            for (int jj = j; jj < NC; jj += 32) {
                float s = b_gen[jj];
                const float* wg = &w_gen[(size_t)jj * HD];
                for (int d = 0; d < HD; d += 4) {
                    float4 wv = *(const float4*)&wg[d];
                    float4 hv = *(const float4*)&hsh[bl][d];
                    s += wv.x * hv.x + wv.y * hv.y + wv.z * hv.z + wv.w * hv.w;
                }
                probs[((size_t)(b0 + bl) * NSTEP + (step - 1)) * NC + jj] = s;
            }
        }
    } else {
#pragma unroll
        for (int it = 0; it < BPB; it++) {
            int idx = tid + it * 256;
            int bl = idx >> 8, hh = idx & 255;
            hsh[bl][hh] = h[(size_t)(b0 + bl) * HD + hh];
        }
    }
    __syncthreads();
    if (step >= NSTEP) return;

    // hp[b][j] = dot(w_h2h[j], h[b]) + b_h2h[j], j = tid
    {
        float acc[BPB];
#pragma unroll
        for (int bl = 0; bl < BPB; bl++) acc[bl] = 0.0f;
        const float* wr = &w_h2h[(size_t)tid * HD];
        for (int d = 0; d < HD; d += 4) {
            float4 wv = *(const float4*)&wr[d];
#pragma unroll
            for (int bl = 0; bl < BPB; bl++) {
                float4 hv = *(const float4*)&hsh[bl][d];
                acc[bl] += wv.x * hv.x + wv.y * hv.y + wv.z * hv.z + wv.w * hv.w;
            }
        }
        float bb = b_h2h[tid];
#pragma unroll
        for (int bl = 0; bl < BPB; bl++)
            hp[(size_t)(b0 + bl) * HD + tid] = acc[bl] + bb;
    }
}

// ---------------------------------------------------------------------------
// K2b: attention scores + softmax + context, ONE batch row per block.
//      1024 blocks x 256 threads -> high memory-level parallelism.
// ---------------------------------------------------------------------------
__global__ __launch_bounds__(256) void attnctx_kernel(
    const float* __restrict__ enc, const float* __restrict__ Hproj,
    const float* __restrict__ hp, const float* __restrict__ w_score,
    float* __restrict__ ctx)
{
    __shared__ float hpsh[HD];
    __shared__ float wssh[HD];
    __shared__ float esh[TT];

    const int tid = threadIdx.x;
    const int b = blockIdx.x;

    hpsh[tid] = hp[(size_t)b * HD + tid];
    wssh[tid] = w_score[tid];
    __syncthreads();

    // e[t]: 8 threads per t, each over 32 d
    {
        int t = tid >> 3, sl = tid & 7;
        int d0 = sl * 32;
        const float* hpr = &Hproj[((size_t)b * TT + t) * HD + d0];
        float e = 0.0f;
#pragma unroll
        for (int d = 0; d < 32; d += 4) {
            float4 hv = *(const float4*)&hpr[d];
            float4 pv = *(const float4*)&hpsh[d0 + d];
            float4 wv = *(const float4*)&wssh[d0 + d];
            e += wv.x * tanhf(hv.x + pv.x);
            e += wv.y * tanhf(hv.y + pv.y);
            e += wv.z * tanhf(hv.z + pv.z);
            e += wv.w * tanhf(hv.w + pv.w);
        }
        e += __shfl_down(e, 4);
        e += __shfl_down(e, 2);
        e += __shfl_down(e, 1);
        if (sl == 0) esh[t] = e;
    }
    __syncthreads();

    // softmax over 32 t-values, lanes 0..31 of wave 0
    if (tid < 32) {
        float v = esh[tid];
        float m = v;
#pragma unroll
        for (int o = 16; o > 0; o >>= 1) m = fmaxf(m, __shfl_xor(m, o));
        float p = expf(v - m);
        float s = p;
#pragma unroll
        for (int o = 16; o > 0; o >>= 1) s += __shfl_xor(s, o);
        esh[tid] = p / s;
    }
    __syncthreads();

    // ctx[b][d] = sum_t alpha[t] * enc[b][t][d], d = tid
    {
        float acc = 0.0f;
        const float* er = &enc[(size_t)b * TT * DIN + tid];
#pragma unroll
        for (int t = 0; t < TT; t++)
            acc += esh[t] * er[(size_t)t * DIN];
        ctx[(size_t)b * DIN + tid] = acc;
    }
}

// ---------------------------------------------------------------------------
extern "C" void kernel_launch(void* const* d_in, const int* in_sizes, int n_in,
                              void* d_out, int out_size, void* d_ws, size_t ws_size,
                              hipStream_t stream)
{
    const float* enc     = (const float*)d_in[0];
    const int*   text    = (const int*)d_in[1];
    const float* w_i2h   = (const float*)d_in[4];
    const float* w_h2h   = (const float*)d_in[5];
    const float* b_h2h   = (const float*)d_in[6];
    const float* w_score = (const float*)d_in[7];
    const float* w_ih    = (const float*)d_in[8];
    const float* w_hh    = (const float*)d_in[9];
    const float* b_ih    = (const float*)d_in[10];
    const float* b_hh    = (const float*)d_in[11];
    const float* w_gen   = (const float*)d_in[12];
    const float* b_gen   = (const float*)d_in[13];
    float* out = (float*)d_out;

    char* ws = (char*)d_ws;
    float* Hproj  = (float*)ws;                                   // 32 MB
    float* hbuf   = (float*)(ws + (size_t)NB * TT * HD * 4);      // 1 MB
    float* cbuf   = hbuf + (size_t)NB * HD;                       // 1 MB
    float* ctxbuf = cbuf + (size_t)NB * HD;                       // 1 MB
    float* gates  = ctxbuf + (size_t)NB * DIN;                    // 4 MB
    float* hpbuf  = gates + (size_t)NB * 4 * HD;                  // 1 MB

    // zero h and c (contiguous)
    hipMemsetAsync(hbuf, 0, (size_t)2 * NB * HD * sizeof(float), stream);

    hproj_kernel<<<dim3(NB * TT / TM, DIN / TN), 256, 0, stream>>>(enc, w_i2h, Hproj);

    for (int s = 0; s < NSTEP; s++) {
        recur_kernel<<<NB / BPB, 256, 0, stream>>>(gates, w_h2h, b_h2h, w_gen, b_gen,
                                                   hbuf, cbuf, hpbuf, out, s);
        attnctx_kernel<<<NB, 256, 0, stream>>>(enc, Hproj, hpbuf, w_score, ctxbuf);
        gates_kernel<<<dim3(NB / TM, 1024 / TN), 256, 0, stream>>>(ctxbuf, hbuf, w_ih, w_hh,
                                                                   b_ih, b_hh, text, s, gates);
    }
    // final LSTM + probs for step 25
    recur_kernel<<<NB / BPB, 256, 0, stream>>>(gates, w_h2h, b_h2h, w_gen, b_gen,
                                               hbuf, cbuf, hpbuf, out, NSTEP);
}